// Round 1
// baseline (542.647 us; speedup 1.0000x reference)
//
#include <hip/hip_runtime.h>
#include <cstdint>
#include <cstddef>

#define N_    16
#define DIM_  2048
#define RF_   256
#define PN_   64
#define TOPK_ 10
#define HW_   128
#define KFULL (DIM_*HW_)   /* 262144 */
#define KMV   (TOPK_*RF_)  /* 2560 */

#define AS1 __attribute__((address_space(1)))
#define AS3 __attribute__((address_space(3)))

typedef __attribute__((ext_vector_type(8))) short bf16x8;
typedef __attribute__((ext_vector_type(4))) float f32x4;

__device__ __forceinline__ unsigned short f2bf(float f) {
  unsigned u = __builtin_bit_cast(unsigned, f);
  unsigned r = (u + 0x7FFFu + ((u >> 16) & 1u)) >> 16;
  return (unsigned short)r;
}

// ---------------------------------------------------------------------------
// Fused fp32->bf16 convert of all 4 weight tensors; zero-inits dsum (1088)
// AND flags (64) — 1152 contiguous words (ws is poisoned 0xAA).
// ---------------------------------------------------------------------------
#define C0 131072
#define C1 1310720
#define C2 1048576
#define C3 1048576
#define CTOT (C0+C1+C2+C3)

__global__ __launch_bounds__(256)
void cvt_all_kernel(const float* __restrict__ s0, const float* __restrict__ s1,
                    const float* __restrict__ s2, const float* __restrict__ s3,
                    unsigned short* __restrict__ d0, unsigned short* __restrict__ d1,
                    unsigned short* __restrict__ d2, unsigned short* __restrict__ d3,
                    float* __restrict__ dsum) {
  int gid = blockIdx.x * blockDim.x + threadIdx.x;
  if (gid < 1152) dsum[gid] = 0.f;
  int stride = gridDim.x * blockDim.x;
  for (int i = gid; i < CTOT; i += stride) {
    const float* s; unsigned short* d; int j = i;
    if (j < C0)            { s = s0; d = d0; }
    else if (j < C0+C1)    { j -= C0; s = s1; d = d1; }
    else if (j < C0+C1+C2) { j -= C0+C1; s = s2; d = d2; }
    else                   { j -= C0+C1+C2; s = s3; d = d3; }
    float4 v = *(const float4*)(s + (size_t)j * 4);
    ushort4 o;
    o.x = f2bf(v.x); o.y = f2bf(v.y); o.z = f2bf(v.z); o.w = f2bf(v.w);
    *(ushort4*)(d + (size_t)j * 4) = o;
  }
}

// ---------------------------------------------------------------------------
// proto [64][2048][128] fp32 -> protoT [64][128][2048] bf16
// ---------------------------------------------------------------------------
__global__ __launch_bounds__(256)
void transpose_proto_kernel(const float* __restrict__ src, unsigned short* __restrict__ dst) {
  __shared__ float tile[32][129];
  const int p = blockIdx.x;
  const int c0 = blockIdx.y * 32;
  const int t = threadIdx.x;
  const float* sp = src + ((size_t)p * DIM_ + c0) * HW_;
#pragma unroll
  for (int i = 0; i < 4; ++i) {
    int g = i * 256 + t;
    int ci = g >> 5, s4 = g & 31;
    float4 v = *(const float4*)(sp + (size_t)ci * HW_ + s4 * 4);
    int sb = s4 * 4;
    tile[ci][sb] = v.x; tile[ci][sb + 1] = v.y; tile[ci][sb + 2] = v.z; tile[ci][sb + 3] = v.w;
  }
  __syncthreads();
  const int s = t >> 1, ch = (t & 1) * 16;
  unsigned short* dp = dst + ((size_t)p * HW_ + s) * DIM_ + c0 + ch;
#pragma unroll
  for (int g = 0; g < 4; ++g) {
    ushort4 pk;
    pk.x = f2bf(tile[ch + g * 4 + 0][s]);
    pk.y = f2bf(tile[ch + g * 4 + 1][s]);
    pk.z = f2bf(tile[ch + g * 4 + 2][s]);
    pk.w = f2bf(tile[ch + g * 4 + 3][s]);
    *(ushort4*)(dp + g * 4) = pk;
  }
}

// ---------------------------------------------------------------------------
// dist partials: 512 blocks; atomicAdd -2*x.p into dsum[n*64+p], ||p||^2 into
// dsum[1024+p] (zeroed by cvt_all).
// ---------------------------------------------------------------------------
__global__ __launch_bounds__(256)
void dist_partial_kernel(const float* __restrict__ x, const float* __restrict__ proto,
                         float* __restrict__ dsum) {
  __shared__ alignas(16) float xl[16][132];
  __shared__ alignas(16) float pl[64][132];
  const int t = threadIdx.x, b = blockIdx.x;
  const int n0 = t & 7;
  const int pb = t >> 3;
  float acc[2][2] = {};
  float pn = 0.f;

  for (int sc = 0; sc < 4; ++sc) {
    const int k0 = b * 512 + sc * 128;
#pragma unroll
    for (int it = 0; it < 2; ++it) {
      int f = it * 256 + t;
      int row = f >> 5, s4 = f & 31;
      *(float4*)&xl[row][s4 * 4] = *(const float4*)(x + (size_t)row * KFULL + k0 + s4 * 4);
    }
#pragma unroll
    for (int it = 0; it < 8; ++it) {
      int f = it * 256 + t;
      int row = f >> 5, s4 = f & 31;
      *(float4*)&pl[row][s4 * 4] = *(const float4*)(proto + (size_t)row * KFULL + k0 + s4 * 4);
    }
    __syncthreads();

#pragma unroll 4
    for (int k = 0; k < 128; k += 4) {
      float4 xa = *(float4*)&xl[n0][k];
      float4 xb = *(float4*)&xl[n0 + 8][k];
      float4 p0 = *(float4*)&pl[pb][k];
      float4 p1 = *(float4*)&pl[pb + 32][k];
      acc[0][0] += xa.x*p0.x + xa.y*p0.y + xa.z*p0.z + xa.w*p0.w;
      acc[0][1] += xa.x*p1.x + xa.y*p1.y + xa.z*p1.z + xa.w*p1.w;
      acc[1][0] += xb.x*p0.x + xb.y*p0.y + xb.z*p0.z + xb.w*p0.w;
      acc[1][1] += xb.x*p1.x + xb.y*p1.y + xb.z*p1.z + xb.w*p1.w;
    }
    if (t < 64) {
#pragma unroll 4
      for (int k = 0; k < 128; k += 4) {
        float4 pv = *(float4*)&pl[t][k];
        pn += pv.x*pv.x + pv.y*pv.y + pv.z*pv.z + pv.w*pv.w;
      }
    }
    __syncthreads();
  }

  atomicAdd(&dsum[n0 * 64 + pb],        -2.f * acc[0][0]);
  atomicAdd(&dsum[n0 * 64 + pb + 32],   -2.f * acc[0][1]);
  atomicAdd(&dsum[(n0+8) * 64 + pb],    -2.f * acc[1][0]);
  atomicAdd(&dsum[(n0+8) * 64 + pb+32], -2.f * acc[1][1]);
  if (t < 64) atomicAdd(&dsum[1024 + t], pn);
}

// ---------------------------------------------------------------------------
// select: rank-based, fully parallel. Block n (16 blocks x 64 lanes): lane p
// ranks its dist among all 64 (stable argsort order); rank<10 -> idx[n][rank].
// flags[] pre-zeroed by cvt_all; benign same-value race across blocks.
// ---------------------------------------------------------------------------
__global__ __launch_bounds__(64)
void select_kernel(const float* __restrict__ dsum, int* __restrict__ idx,
                   int* __restrict__ flags) {
  __shared__ float sh[64];
  const int n = blockIdx.x, t = threadIdx.x;
  float dval = dsum[1024 + t] + dsum[n * 64 + t];
  sh[t] = dval;
  __syncthreads();
  int rank = 0;
#pragma unroll
  for (int j = 0; j < 64; ++j) {
    float o = sh[j];
    rank += (o < dval || (o == dval && j < t)) ? 1 : 0;
  }
  if (rank < TOPK_) { idx[n * TOPK_ + rank] = t; flags[t] = 1; }
}

// ---------------------------------------------------------------------------
// bf16 MFMA GEMM, double-buffered, one barrier/iter. Tile 32Mx128Nx64K.
// 128 threads = 2 waves; wave-tile 32x64 = 2x4 of 16x16x32.
// Occupancy redesign vs previous (64M tile): grid doubles (1024 blocks for
// the DIM-output GEMMs) and LDS is exactly 40960 B -> 4 blocks/CU
// (8 waves/CU, 2/SIMD, 4 independent barrier domains) instead of 2 blocks
// at 1 wave/SIMD. MODE1 proto ids live in a register (__shfl), MODE2
// nsum/nsq scratch aliases the dead A buffer, so nothing pushes LDS past
// the 160KB/4 boundary.
// LDS k-quad-major: A cell(qk,m)=16B @ qk*512B + m*16B; B cell(qk,n) =
// qk*2048B + n*16B. global_load_lds width=16, lane-contiguous by design.
// ---------------------------------------------------------------------------
#define BM 32
#define BKK 64

template <int MODE>
__global__ __launch_bounds__(128, 2)
void mfma_gemm_kernel(const unsigned short* __restrict__ Wb,
                      const unsigned short* __restrict__ Xb,
                      void* __restrict__ OutP,
                      const float* __restrict__ inputs,
                      const int* __restrict__ idxp,
                      const int* __restrict__ flags,
                      int K, int O, int Ldim) {
  __shared__ alignas(16) unsigned short Al[2][8 * BM * 8];    // 2 x 4 KB
  __shared__ alignas(16) unsigned short Bl[2][8 * 128 * 8];   // 2 x 16 KB

  const int t = threadIdx.x;
  const int w = t >> 6;          // wave 0/1 -> n-half
  const int lane = t & 63;
  const int q = lane >> 4;
  const int l15 = lane & 15;
  const int batch = blockIdx.y;
  const int o0 = blockIdx.x * BM;

  if (MODE == 0 && flags && !flags[batch]) return;

  int idreg = 0;
  if (MODE == 1 && lane < TOPK_) idreg = idxp[batch * TOPK_ + lane];

  f32x4 acc[2][4] = {};

  auto issue = [&](int k0, int buf) {
    // A: wave w stages loads v=2w..2w+1; each load covers k-quads {2v,2v+1}
    // (32 rows each). lane -> (qk = 2v + (lane>>5), m = lane&31); LDS dest
    // base is wave-uniform, HW adds lane*16B which lands exactly at
    // qk*512B + m*16B.
#pragma unroll
    for (int i = 0; i < 2; ++i) {
      int v = w * 2 + i;
      const unsigned short* ga =
          Wb + (size_t)(o0 + (lane & 31)) * K + k0 + (v * 2 + (lane >> 5)) * 8;
      __builtin_amdgcn_global_load_lds((const AS1 void*)ga,
                                       (AS3 void*)(&Al[buf][v * 512]), 16, 0, 0);
    }
    const unsigned short* base; int rs;
    if (MODE == 1) {
      int id = __shfl(idreg, k0 >> 8, 64);
      base = Xb + (size_t)id * (HW_ * RF_) + (k0 & 255);
      rs = RF_;
    } else {
      base = Xb + (size_t)batch * HW_ * K + k0;
      rs = K;
    }
    // B: wave w stages 8 of 16 (qk, half) regions
#pragma unroll
    for (int i = 0; i < 8; ++i) {
      int v = w * 8 + i;
      int qk = v >> 1, h = v & 1;
      const unsigned short* gb = base + (size_t)(h * 64 + lane) * rs + qk * 8;
      __builtin_amdgcn_global_load_lds((const AS1 void*)gb,
                                       (AS3 void*)(&Bl[buf][qk * 1024 + h * 512]), 16, 0, 0);
    }
  };

  issue(0, 0);
  __syncthreads();

  const int nIter = K / BKK;
  for (int it = 0; it < nIter; ++it) {
    const int buf = it & 1;
    if (it + 1 < nIter) issue((it + 1) * BKK, buf ^ 1);
#pragma unroll
    for (int s = 0; s < 2; ++s) {
      bf16x8 af[2], bfr[4];
#pragma unroll
      for (int mt = 0; mt < 2; ++mt)
        af[mt] = *(const bf16x8*)(&Al[buf][(s * 4 + q) * 256 + (mt * 16 + l15) * 8]);
#pragma unroll
      for (int nt = 0; nt < 4; ++nt)
        bfr[nt] = *(const bf16x8*)(&Bl[buf][(s * 4 + q) * 1024 + (w * 64 + nt * 16 + l15) * 8]);
#pragma unroll
      for (int mt = 0; mt < 2; ++mt)
#pragma unroll
        for (int nt = 0; nt < 4; ++nt)
          acc[mt][nt] = __builtin_amdgcn_mfma_f32_16x16x32_bf16(af[mt], bfr[nt], acc[mt][nt], 0, 0, 0);
    }
    __syncthreads();
  }

  // ---------------- epilogue ----------------
  const float CAL = 1.0f - 1.0f / 262144.0f;

  // MODE2 scratch aliases the A buffer (dead after the K-loop; the loop's
  // final __syncthreads separates the last LDS reads from these writes).
  float* nsumS = (float*)&Al[0][0];        // [2][32]
  float* nsqS  = (float*)&Al[0][0] + 64;   // [2][32]

  if (MODE == 2) {
#pragma unroll
    for (int mt = 0; mt < 2; ++mt)
#pragma unroll
      for (int reg = 0; reg < 4; ++reg) {
        float s_ = 0.f, q_ = 0.f;
#pragma unroll
        for (int nt = 0; nt < 4; ++nt) {
          float v = acc[mt][nt][reg];
          s_ += v; q_ += v * v;
        }
#pragma unroll
        for (int m = 1; m < 16; m <<= 1) {
          s_ += __shfl_xor(s_, m, 64);
          q_ += __shfl_xor(q_, m, 64);
        }
        if (l15 == 0) {
          int ol = mt * 16 + q * 4 + reg;
          nsumS[w * 32 + ol] = s_; nsqS[w * 32 + ol] = q_;
        }
      }
    __syncthreads();
  }

  if (MODE == 3) {
    float* ofb = (float*)OutP + (size_t)batch * DIM_ * HW_;
    const float* inb = inputs + (size_t)batch * DIM_ * HW_;
#pragma unroll
    for (int mt = 0; mt < 2; ++mt)
#pragma unroll
      for (int nt = 0; nt < 4; ++nt) {
        int o = o0 + mt * 16 + q * 4;
        int s = w * 64 + nt * 16 + l15;
        f32x4 v = acc[mt][nt];
#pragma unroll
        for (int g = 0; g < 4; ++g) {
          float in = inb[(size_t)(o + g) * HW_ + s];
          float sg = 1.f / (1.f + expf(-v[g]));
          ofb[(size_t)(o + g) * HW_ + s] = in * (1.f + sg);
        }
      }
  } else {
    unsigned short* ob = (unsigned short*)OutP + (size_t)batch * HW_ * Ldim;
    const float* inb = (MODE == 1) ? inputs + (size_t)batch * DIM_ * HW_ : nullptr;
#pragma unroll
    for (int mt = 0; mt < 2; ++mt) {
      float mean[4], rs[4];
      if (MODE == 2) {
#pragma unroll
        for (int reg = 0; reg < 4; ++reg) {
          int ol = mt * 16 + q * 4 + reg;
          float ts = nsumS[ol] + nsumS[32 + ol];
          float tq = nsqS[ol] + nsqS[32 + ol];
          float mn = ts * (1.f / 128.f);
          float vr = tq * (1.f / 128.f) - mn * mn;
          mean[reg] = mn; rs[reg] = rsqrtf(vr + 1e-5f);
        }
      }
#pragma unroll
      for (int nt = 0; nt < 4; ++nt) {
        int o = o0 + mt * 16 + q * 4;
        int s = w * 64 + nt * 16 + l15;
        f32x4 v = acc[mt][nt];
        float r[4];
        if (MODE == 0) {
#pragma unroll
          for (int g = 0; g < 4; ++g) r[g] = v[g];
        } else if (MODE == 1) {
          const float* ip = inb + (size_t)o * HW_ + s;
#pragma unroll
          for (int g = 0; g < 4; ++g)
            r[g] = fmaxf(0.f, 0.5f * ip[(size_t)g * HW_] + CAL * v[g]);
        } else {
#pragma unroll
          for (int g = 0; g < 4; ++g) r[g] = (v[g] - mean[g]) * rs[g];
        }
        ushort4 pk;
        pk.x = f2bf(r[0]); pk.y = f2bf(r[1]); pk.z = f2bf(r[2]); pk.w = f2bf(r[3]);
        *(ushort4*)(ob + (size_t)s * Ldim + o) = pk;
      }
    }
  }
}

// ---------------------------------------------------------------------------
extern "C" void kernel_launch(void* const* d_in, const int* in_sizes, int n_in,
                              void* d_out, int out_size, void* d_ws, size_t ws_size,
                              hipStream_t stream) {
  const float* inputs = (const float*)d_in[0];
  const float* proto  = (const float*)d_in[1];
  const float* w_rf   = (const float*)d_in[2];
  const float* w_rfmv = (const float*)d_in[3];
  const float* w_rms  = (const float*)d_in[4];
  const float* w_fuse = (const float*)d_in[5];
  float* out = (float*)d_out;

  uint8_t* ws = (uint8_t*)d_ws;
  size_t off = 0;
  auto alloc = [&](size_t bytes) { uint8_t* p = ws + off; off += (bytes + 255) & ~(size_t)255; return p; };

  float* dsum  = (float*)alloc(1088 * 4);       // 4352 B (256-aligned size)
  int*   flags = (int*)alloc(PN_ * 4);          // contiguous after dsum -> zeroed together
  int*   idx   = (int*)alloc(N_ * TOPK_ * 4);
  unsigned short* wrf_b   = (unsigned short*)alloc((size_t)RF_ * DIM_ * 2);
  unsigned short* wrfmv_b = (unsigned short*)alloc((size_t)DIM_ * KMV * 2);
  unsigned short* wrms_b  = (unsigned short*)alloc((size_t)DIM_ * DIM_ * 2);
  unsigned short* wfuse_b = (unsigned short*)alloc((size_t)DIM_ * DIM_ * 2);
  unsigned short* xpT     = (unsigned short*)alloc((size_t)PN_ * HW_ * RF_ * 2);
  unsigned short* protoT  = (unsigned short*)alloc((size_t)PN_ * HW_ * DIM_ * 2);
  unsigned short* mvlT = protoT;                 // aliases (protoT dead after G1)
  unsigned short* mvaT = protoT + (size_t)N_ * HW_ * DIM_;

  cvt_all_kernel<<<1024, 256, 0, stream>>>(w_rf, w_rfmv, w_rms, w_fuse,
                                           wrf_b, wrfmv_b, wrms_b, wfuse_b, dsum);
  transpose_proto_kernel<<<dim3(PN_, DIM_ / 32), 256, 0, stream>>>(proto, protoT);
  dist_partial_kernel<<<512, 256, 0, stream>>>(inputs, proto, dsum);
  select_kernel<<<N_, 64, 0, stream>>>(dsum, idx, flags);

  mfma_gemm_kernel<0><<<dim3(RF_ / BM, PN_), 128, 0, stream>>>(
      wrf_b, protoT, xpT, nullptr, nullptr, flags, DIM_, RF_, RF_);
  mfma_gemm_kernel<1><<<dim3(DIM_ / BM, N_), 128, 0, stream>>>(
      wrfmv_b, xpT, mvlT, inputs, idx, nullptr, KMV, DIM_, DIM_);
  mfma_gemm_kernel<2><<<dim3(DIM_ / BM, N_), 128, 0, stream>>>(
      wrms_b, mvlT, mvaT, nullptr, nullptr, nullptr, DIM_, DIM_, DIM_);
  mfma_gemm_kernel<3><<<dim3(DIM_ / BM, N_), 128, 0, stream>>>(
      wfuse_b, mvaT, out, inputs, nullptr, nullptr, DIM_, DIM_, DIM_);
}

// Round 2
// 432.283 us; speedup vs baseline: 1.2553x; 1.2553x over previous
//
#include <hip/hip_runtime.h>
#include <cstdint>
#include <cstddef>

#define N_    16
#define DIM_  2048
#define RF_   256
#define PN_   64
#define TOPK_ 10
#define HW_   128
#define KFULL (DIM_*HW_)   /* 262144 */
#define KMV   (TOPK_*RF_)  /* 2560 */

#define AS1 __attribute__((address_space(1)))
#define AS3 __attribute__((address_space(3)))

typedef __attribute__((ext_vector_type(8))) short bf16x8;
typedef __attribute__((ext_vector_type(4))) float f32x4;

__device__ __forceinline__ unsigned short f2bf(float f) {
  unsigned u = __builtin_bit_cast(unsigned, f);
  unsigned r = (u + 0x7FFFu + ((u >> 16) & 1u)) >> 16;
  return (unsigned short)r;
}

// ---------------------------------------------------------------------------
// Fused fp32->bf16 convert of all 4 weight tensors; zero-inits dsum (1088)
// AND flags (64) — 1152 contiguous words (ws is poisoned 0xAA).
// ---------------------------------------------------------------------------
#define C0 131072
#define C1 1310720
#define C2 1048576
#define C3 1048576
#define CTOT (C0+C1+C2+C3)

__global__ __launch_bounds__(256)
void cvt_all_kernel(const float* __restrict__ s0, const float* __restrict__ s1,
                    const float* __restrict__ s2, const float* __restrict__ s3,
                    unsigned short* __restrict__ d0, unsigned short* __restrict__ d1,
                    unsigned short* __restrict__ d2, unsigned short* __restrict__ d3,
                    float* __restrict__ dsum) {
  int gid = blockIdx.x * blockDim.x + threadIdx.x;
  if (gid < 1152) dsum[gid] = 0.f;
  int stride = gridDim.x * blockDim.x;
  for (int i = gid; i < CTOT; i += stride) {
    const float* s; unsigned short* d; int j = i;
    if (j < C0)            { s = s0; d = d0; }
    else if (j < C0+C1)    { j -= C0; s = s1; d = d1; }
    else if (j < C0+C1+C2) { j -= C0+C1; s = s2; d = d2; }
    else                   { j -= C0+C1+C2; s = s3; d = d3; }
    float4 v = *(const float4*)(s + (size_t)j * 4);
    ushort4 o;
    o.x = f2bf(v.x); o.y = f2bf(v.y); o.z = f2bf(v.z); o.w = f2bf(v.w);
    *(ushort4*)(d + (size_t)j * 4) = o;
  }
}

// ---------------------------------------------------------------------------
// proto [64][2048][128] fp32 -> protoT [64][128][2048] bf16
// ---------------------------------------------------------------------------
__global__ __launch_bounds__(256)
void transpose_proto_kernel(const float* __restrict__ src, unsigned short* __restrict__ dst) {
  __shared__ float tile[32][129];
  const int p = blockIdx.x;
  const int c0 = blockIdx.y * 32;
  const int t = threadIdx.x;
  const float* sp = src + ((size_t)p * DIM_ + c0) * HW_;
#pragma unroll
  for (int i = 0; i < 4; ++i) {
    int g = i * 256 + t;
    int ci = g >> 5, s4 = g & 31;
    float4 v = *(const float4*)(sp + (size_t)ci * HW_ + s4 * 4);
    int sb = s4 * 4;
    tile[ci][sb] = v.x; tile[ci][sb + 1] = v.y; tile[ci][sb + 2] = v.z; tile[ci][sb + 3] = v.w;
  }
  __syncthreads();
  const int s = t >> 1, ch = (t & 1) * 16;
  unsigned short* dp = dst + ((size_t)p * HW_ + s) * DIM_ + c0 + ch;
#pragma unroll
  for (int g = 0; g < 4; ++g) {
    ushort4 pk;
    pk.x = f2bf(tile[ch + g * 4 + 0][s]);
    pk.y = f2bf(tile[ch + g * 4 + 1][s]);
    pk.z = f2bf(tile[ch + g * 4 + 2][s]);
    pk.w = f2bf(tile[ch + g * 4 + 3][s]);
    *(ushort4*)(dp + g * 4) = pk;
  }
}

// ---------------------------------------------------------------------------
// dist partials: 512 blocks; atomicAdd -2*x.p into dsum[n*64+p], ||p||^2 into
// dsum[1024+p] (zeroed by cvt_all).
// ---------------------------------------------------------------------------
__global__ __launch_bounds__(256)
void dist_partial_kernel(const float* __restrict__ x, const float* __restrict__ proto,
                         float* __restrict__ dsum) {
  __shared__ alignas(16) float xl[16][132];
  __shared__ alignas(16) float pl[64][132];
  const int t = threadIdx.x, b = blockIdx.x;
  const int n0 = t & 7;
  const int pb = t >> 3;
  float acc[2][2] = {};
  float pn = 0.f;

  for (int sc = 0; sc < 4; ++sc) {
    const int k0 = b * 512 + sc * 128;
#pragma unroll
    for (int it = 0; it < 2; ++it) {
      int f = it * 256 + t;
      int row = f >> 5, s4 = f & 31;
      *(float4*)&xl[row][s4 * 4] = *(const float4*)(x + (size_t)row * KFULL + k0 + s4 * 4);
    }
#pragma unroll
    for (int it = 0; it < 8; ++it) {
      int f = it * 256 + t;
      int row = f >> 5, s4 = f & 31;
      *(float4*)&pl[row][s4 * 4] = *(const float4*)(proto + (size_t)row * KFULL + k0 + s4 * 4);
    }
    __syncthreads();

#pragma unroll 4
    for (int k = 0; k < 128; k += 4) {
      float4 xa = *(float4*)&xl[n0][k];
      float4 xb = *(float4*)&xl[n0 + 8][k];
      float4 p0 = *(float4*)&pl[pb][k];
      float4 p1 = *(float4*)&pl[pb + 32][k];
      acc[0][0] += xa.x*p0.x + xa.y*p0.y + xa.z*p0.z + xa.w*p0.w;
      acc[0][1] += xa.x*p1.x + xa.y*p1.y + xa.z*p1.z + xa.w*p1.w;
      acc[1][0] += xb.x*p0.x + xb.y*p0.y + xb.z*p0.z + xb.w*p0.w;
      acc[1][1] += xb.x*p1.x + xb.y*p1.y + xb.z*p1.z + xb.w*p1.w;
    }
    if (t < 64) {
#pragma unroll 4
      for (int k = 0; k < 128; k += 4) {
        float4 pv = *(float4*)&pl[t][k];
        pn += pv.x*pv.x + pv.y*pv.y + pv.z*pv.z + pv.w*pv.w;
      }
    }
    __syncthreads();
  }

  atomicAdd(&dsum[n0 * 64 + pb],        -2.f * acc[0][0]);
  atomicAdd(&dsum[n0 * 64 + pb + 32],   -2.f * acc[0][1]);
  atomicAdd(&dsum[(n0+8) * 64 + pb],    -2.f * acc[1][0]);
  atomicAdd(&dsum[(n0+8) * 64 + pb+32], -2.f * acc[1][1]);
  if (t < 64) atomicAdd(&dsum[1024 + t], pn);
}

// ---------------------------------------------------------------------------
// select: rank-based, fully parallel. Block n (16 blocks x 64 lanes): lane p
// ranks its dist among all 64 (stable argsort order); rank<10 -> idx[n][rank].
// flags[] pre-zeroed by cvt_all; benign same-value race across blocks.
// ---------------------------------------------------------------------------
__global__ __launch_bounds__(64)
void select_kernel(const float* __restrict__ dsum, int* __restrict__ idx,
                   int* __restrict__ flags) {
  __shared__ float sh[64];
  const int n = blockIdx.x, t = threadIdx.x;
  float dval = dsum[1024 + t] + dsum[n * 64 + t];
  sh[t] = dval;
  __syncthreads();
  int rank = 0;
#pragma unroll
  for (int j = 0; j < 64; ++j) {
    float o = sh[j];
    rank += (o < dval || (o == dval && j < t)) ? 1 : 0;
  }
  if (rank < TOPK_) { idx[n * TOPK_ + rank] = t; flags[t] = 1; }
}

// ---------------------------------------------------------------------------
// bf16 MFMA GEMM, tile 64Mx128Nx64K, 128 threads = 2 waves, wave-tile 64x64
// = 4x4 of 16x16x32 (round-0 geometry, 12 global_load_lds per wave per
// K-step).
//
// T3/T4 pipeline (this round's change): TRIPLE-buffered LDS with a 2-deep
// prefetch and COUNTED vmcnt. Stage it+2 is issued at the bottom of iter it;
// before computing stage it we wait only vmcnt(12) (my wave's stage-it loads
// done; the 12 newer stage-(it+1) loads stay in flight across the raw
// s_barrier). __syncthreads (vmcnt(0) drain) appears nowhere in the loop —
// the full L2/HBM round trip per iteration was the measured ~6100-cyc/iter
// bottleneck (MfmaUtil 7.6% at both 2 and 4 blocks/CU).
//
// Buffer-reuse hazard: issue(it+2) writes buffer (it+2)%3 == buffer of stage
// it-1; every wave finished compute(it-1) before barrier(it), which precedes
// issue(it+2) in program order -> safe. MODE2 nsum/nsq alias Al buffer 0:
// last stage of the K=2048 loop is buf (31%3)=1, so epilogue writes to buf 0
// can't race the other wave's final compute.
//
// LDS: 3 x (8KB A + 16KB B) = 72 KB -> 2 blocks/CU, grid 512 = exact fit.
// LDS k-quad-major: A cell(qk,m)=16B @ qk*1024B + m*16B; B cell(qk,n) =
// qk*2048B + n*16B. global_load_lds width=16, lane-contiguous by design.
// ---------------------------------------------------------------------------
#define BM 64
#define BKK 64

template <int MODE>
__global__ __launch_bounds__(128, 2)
void mfma_gemm_kernel(const unsigned short* __restrict__ Wb,
                      const unsigned short* __restrict__ Xb,
                      void* __restrict__ OutP,
                      const float* __restrict__ inputs,
                      const int* __restrict__ idxp,
                      const int* __restrict__ flags,
                      int K, int O, int Ldim) {
  __shared__ alignas(16) unsigned short Al[3][8 * BM * 8];    // 3 x 8 KB
  __shared__ alignas(16) unsigned short Bl[3][8 * 128 * 8];   // 3 x 16 KB

  const int t = threadIdx.x;
  const int w = t >> 6;          // wave 0/1 -> n-half
  const int lane = t & 63;
  const int q = lane >> 4;
  const int l15 = lane & 15;
  const int batch = blockIdx.y;
  const int o0 = blockIdx.x * BM;

  if (MODE == 0 && flags && !flags[batch]) return;

  int idreg = 0;
  if (MODE == 1 && lane < TOPK_) idreg = idxp[batch * TOPK_ + lane];

  f32x4 acc[4][4] = {};

  auto issue = [&](int k0, int buf) {
    // A: wave w stages k-quads 4w..4w+3 (64 rows each, lane = m)
#pragma unroll
    for (int i = 0; i < 4; ++i) {
      int qk = w * 4 + i;
      const unsigned short* ga = Wb + (size_t)(o0 + lane) * K + k0 + qk * 8;
      __builtin_amdgcn_global_load_lds((const AS1 void*)ga,
                                       (AS3 void*)(&Al[buf][qk * 512]), 16, 0, 0);
    }
    const unsigned short* base; int rs;
    if (MODE == 1) {
      int id = __shfl(idreg, k0 >> 8, 64);
      base = Xb + (size_t)id * (HW_ * RF_) + (k0 & 255);
      rs = RF_;
    } else {
      base = Xb + (size_t)batch * HW_ * K + k0;
      rs = K;
    }
    // B: wave w stages 8 of 16 (qk, half) regions
#pragma unroll
    for (int i = 0; i < 8; ++i) {
      int v = w * 8 + i;
      int qk = v >> 1, h = v & 1;
      const unsigned short* gb = base + (size_t)(h * 64 + lane) * rs + qk * 8;
      __builtin_amdgcn_global_load_lds((const AS1 void*)gb,
                                       (AS3 void*)(&Bl[buf][qk * 1024 + h * 512]), 16, 0, 0);
    }
  };

  const int nIter = K / BKK;   // 32 (MODE 0/2/3) or 40 (MODE 1)

  issue(0, 0);
  issue(BKK, 1);               // 24 loads/wave outstanding

  for (int it = 0; it < nIter; ++it) {
    const int buf = it % 3;
    // Counted wait: stage-it loads (oldest 12) landed; stage-(it+1) loads
    // stay in flight across the barrier. Full drain only on the last iter.
    if (it + 1 < nIter) {
      asm volatile("s_waitcnt vmcnt(12)" ::: "memory");
    } else {
      asm volatile("s_waitcnt vmcnt(0)" ::: "memory");
    }
    __builtin_amdgcn_s_barrier();
#pragma unroll
    for (int s = 0; s < 2; ++s) {
      bf16x8 af[4], bfr[4];
#pragma unroll
      for (int mt = 0; mt < 4; ++mt)
        af[mt] = *(const bf16x8*)(&Al[buf][(s * 4 + q) * 512 + (mt * 16 + l15) * 8]);
#pragma unroll
      for (int nt = 0; nt < 4; ++nt)
        bfr[nt] = *(const bf16x8*)(&Bl[buf][(s * 4 + q) * 1024 + (w * 64 + nt * 16 + l15) * 8]);
#pragma unroll
      for (int mt = 0; mt < 4; ++mt)
#pragma unroll
        for (int nt = 0; nt < 4; ++nt)
          acc[mt][nt] = __builtin_amdgcn_mfma_f32_16x16x32_bf16(af[mt], bfr[nt], acc[mt][nt], 0, 0, 0);
    }
    if (it + 2 < nIter) issue((it + 2) * BKK, (it + 2) % 3);
  }

  // ---------------- epilogue ----------------
  const float CAL = 1.0f - 1.0f / 262144.0f;

  // MODE2 scratch aliases Al buffer 0 (safe: last K-stage uses buffer 1).
  float* nsumS = (float*)&Al[0][0];         // [2][64]
  float* nsqS  = (float*)&Al[0][0] + 128;   // [2][64]

  if (MODE == 2) {
#pragma unroll
    for (int mt = 0; mt < 4; ++mt)
#pragma unroll
      for (int reg = 0; reg < 4; ++reg) {
        float s_ = 0.f, q_ = 0.f;
#pragma unroll
        for (int nt = 0; nt < 4; ++nt) {
          float v = acc[mt][nt][reg];
          s_ += v; q_ += v * v;
        }
#pragma unroll
        for (int m = 1; m < 16; m <<= 1) {
          s_ += __shfl_xor(s_, m, 64);
          q_ += __shfl_xor(q_, m, 64);
        }
        if (l15 == 0) {
          int ol = mt * 16 + q * 4 + reg;
          nsumS[w * 64 + ol] = s_; nsqS[w * 64 + ol] = q_;
        }
      }
    __syncthreads();
  }

  if (MODE == 3) {
    float* ofb = (float*)OutP + (size_t)batch * DIM_ * HW_;
    const float* inb = inputs + (size_t)batch * DIM_ * HW_;
#pragma unroll
    for (int mt = 0; mt < 4; ++mt)
#pragma unroll
      for (int nt = 0; nt < 4; ++nt) {
        int o = o0 + mt * 16 + q * 4;
        int s = w * 64 + nt * 16 + l15;
        f32x4 v = acc[mt][nt];
#pragma unroll
        for (int g = 0; g < 4; ++g) {
          float in = inb[(size_t)(o + g) * HW_ + s];
          float sg = 1.f / (1.f + expf(-v[g]));
          ofb[(size_t)(o + g) * HW_ + s] = in * (1.f + sg);
        }
      }
  } else {
    unsigned short* ob = (unsigned short*)OutP + (size_t)batch * HW_ * Ldim;
    const float* inb = (MODE == 1) ? inputs + (size_t)batch * DIM_ * HW_ : nullptr;
#pragma unroll
    for (int mt = 0; mt < 4; ++mt) {
      float mean[4], rs[4];
      if (MODE == 2) {
#pragma unroll
        for (int reg = 0; reg < 4; ++reg) {
          int ol = mt * 16 + q * 4 + reg;
          float ts = nsumS[ol] + nsumS[64 + ol];
          float tq = nsqS[ol] + nsqS[64 + ol];
          float mn = ts * (1.f / 128.f);
          float vr = tq * (1.f / 128.f) - mn * mn;
          mean[reg] = mn; rs[reg] = rsqrtf(vr + 1e-5f);
        }
      }
#pragma unroll
      for (int nt = 0; nt < 4; ++nt) {
        int o = o0 + mt * 16 + q * 4;
        int s = w * 64 + nt * 16 + l15;
        f32x4 v = acc[mt][nt];
        float r[4];
        if (MODE == 0) {
#pragma unroll
          for (int g = 0; g < 4; ++g) r[g] = v[g];
        } else if (MODE == 1) {
          const float* ip = inb + (size_t)o * HW_ + s;
#pragma unroll
          for (int g = 0; g < 4; ++g)
            r[g] = fmaxf(0.f, 0.5f * ip[(size_t)g * HW_] + CAL * v[g]);
        } else {
#pragma unroll
          for (int g = 0; g < 4; ++g) r[g] = (v[g] - mean[g]) * rs[g];
        }
        ushort4 pk;
        pk.x = f2bf(r[0]); pk.y = f2bf(r[1]); pk.z = f2bf(r[2]); pk.w = f2bf(r[3]);
        *(ushort4*)(ob + (size_t)s * Ldim + o) = pk;
      }
    }
  }
}

// ---------------------------------------------------------------------------
extern "C" void kernel_launch(void* const* d_in, const int* in_sizes, int n_in,
                              void* d_out, int out_size, void* d_ws, size_t ws_size,
                              hipStream_t stream) {
  const float* inputs = (const float*)d_in[0];
  const float* proto  = (const float*)d_in[1];
  const float* w_rf   = (const float*)d_in[2];
  const float* w_rfmv = (const float*)d_in[3];
  const float* w_rms  = (const float*)d_in[4];
  const float* w_fuse = (const float*)d_in[5];
  float* out = (float*)d_out;

  uint8_t* ws = (uint8_t*)d_ws;
  size_t off = 0;
  auto alloc = [&](size_t bytes) { uint8_t* p = ws + off; off += (bytes + 255) & ~(size_t)255; return p; };

  float* dsum  = (float*)alloc(1088 * 4);       // 4352 B (256-aligned size)
  int*   flags = (int*)alloc(PN_ * 4);          // contiguous after dsum -> zeroed together
  int*   idx   = (int*)alloc(N_ * TOPK_ * 4);
  unsigned short* wrf_b   = (unsigned short*)alloc((size_t)RF_ * DIM_ * 2);
  unsigned short* wrfmv_b = (unsigned short*)alloc((size_t)DIM_ * KMV * 2);
  unsigned short* wrms_b  = (unsigned short*)alloc((size_t)DIM_ * DIM_ * 2);
  unsigned short* wfuse_b = (unsigned short*)alloc((size_t)DIM_ * DIM_ * 2);
  unsigned short* xpT     = (unsigned short*)alloc((size_t)PN_ * HW_ * RF_ * 2);
  unsigned short* protoT  = (unsigned short*)alloc((size_t)PN_ * HW_ * DIM_ * 2);
  unsigned short* mvlT = protoT;                 // aliases (protoT dead after G1)
  unsigned short* mvaT = protoT + (size_t)N_ * HW_ * DIM_;

  cvt_all_kernel<<<1024, 256, 0, stream>>>(w_rf, w_rfmv, w_rms, w_fuse,
                                           wrf_b, wrfmv_b, wrms_b, wfuse_b, dsum);
  transpose_proto_kernel<<<dim3(PN_, DIM_ / 32), 256, 0, stream>>>(proto, protoT);
  dist_partial_kernel<<<512, 256, 0, stream>>>(inputs, proto, dsum);
  select_kernel<<<N_, 64, 0, stream>>>(dsum, idx, flags);

  mfma_gemm_kernel<0><<<dim3(RF_ / BM, PN_), 128, 0, stream>>>(
      wrf_b, protoT, xpT, nullptr, nullptr, flags, DIM_, RF_, RF_);
  mfma_gemm_kernel<1><<<dim3(DIM_ / BM, N_), 128, 0, stream>>>(
      wrfmv_b, xpT, mvlT, inputs, idx, nullptr, KMV, DIM_, DIM_);
  mfma_gemm_kernel<2><<<dim3(DIM_ / BM, N_), 128, 0, stream>>>(
      wrms_b, mvlT, mvaT, nullptr, nullptr, nullptr, DIM_, DIM_, DIM_);
  mfma_gemm_kernel<3><<<dim3(DIM_ / BM, N_), 128, 0, stream>>>(
      wfuse_b, mvaT, out, inputs, nullptr, nullptr, DIM_, DIM_, DIM_);
}

// Round 3
// 376.519 us; speedup vs baseline: 1.4412x; 1.1481x over previous
//
#include <hip/hip_runtime.h>
#include <cstdint>
#include <cstddef>

#define N_    16
#define DIM_  2048
#define RF_   256
#define PN_   64
#define TOPK_ 10
#define HW_   128
#define KFULL (DIM_*HW_)   /* 262144 */
#define KMV   (TOPK_*RF_)  /* 2560 */

#define AS1 __attribute__((address_space(1)))
#define AS3 __attribute__((address_space(3)))

typedef __attribute__((ext_vector_type(8))) short bf16x8;
typedef __attribute__((ext_vector_type(4))) float f32x4;
typedef __attribute__((ext_vector_type(8))) unsigned short u16x8;

__device__ __forceinline__ unsigned short f2bf(float f) {
  unsigned u = __builtin_bit_cast(unsigned, f);
  unsigned r = (u + 0x7FFFu + ((u >> 16) & 1u)) >> 16;
  return (unsigned short)r;
}

// ---------------------------------------------------------------------------
// Weight convert fp32 [O][C] row-major -> bf16 k-quad-major W'[C/8][O][8].
// Consumer (GEMM A-stage) then reads one contiguous 1KB run per wave-load
// (lane*16B), instead of a 64-line gather at 2*K-byte lane stride.
// Reads stay coalesced (adjacent threads = adjacent 32B of the same row);
// writes scatter at O*16B stride — acceptable: this kernel moves only 14MB.
// ---------------------------------------------------------------------------
template <int O, int C>
__device__ __forceinline__ void cvt_tensor(const float* __restrict__ s,
                                           unsigned short* __restrict__ d,
                                           int gid, int stride) {
  const int G = O * (C / 8);
  for (int j = gid; j < G; j += stride) {
    int o = j / (C / 8);
    int cg = j - o * (C / 8);
    const float4 a = *(const float4*)(s + (size_t)o * C + (size_t)cg * 8);
    const float4 b = *(const float4*)(s + (size_t)o * C + (size_t)cg * 8 + 4);
    u16x8 pk;
    pk[0] = f2bf(a.x); pk[1] = f2bf(a.y); pk[2] = f2bf(a.z); pk[3] = f2bf(a.w);
    pk[4] = f2bf(b.x); pk[5] = f2bf(b.y); pk[6] = f2bf(b.z); pk[7] = f2bf(b.w);
    *(u16x8*)(d + (size_t)cg * (O * 8) + (size_t)o * 8) = pk;
  }
}

__global__ __launch_bounds__(256)
void cvt_all_kernel(const float* __restrict__ s0, const float* __restrict__ s1,
                    const float* __restrict__ s2, const float* __restrict__ s3,
                    unsigned short* __restrict__ d0, unsigned short* __restrict__ d1,
                    unsigned short* __restrict__ d2, unsigned short* __restrict__ d3,
                    float* __restrict__ dsum) {
  int gid = blockIdx.x * blockDim.x + threadIdx.x;
  if (gid < 1152) dsum[gid] = 0.f;   // dsum (1088) + flags (64), contiguous
  int stride = gridDim.x * blockDim.x;
  cvt_tensor<RF_,  DIM_>(s0, d0, gid, stride);
  cvt_tensor<DIM_, KMV >(s1, d1, gid, stride);
  cvt_tensor<DIM_, DIM_>(s2, d2, gid, stride);
  cvt_tensor<DIM_, DIM_>(s3, d3, gid, stride);
}

// ---------------------------------------------------------------------------
// proto [64][2048][128] fp32 -> protoT' [64][kq=256][s=128][8] bf16
// (k-quad-major). Writes are contiguous 1KB per 64 lanes.
// ---------------------------------------------------------------------------
__global__ __launch_bounds__(256)
void transpose_proto_kernel(const float* __restrict__ src, unsigned short* __restrict__ dst) {
  __shared__ float tile[32][129];
  const int p = blockIdx.x;
  const int c0 = blockIdx.y * 32;
  const int t = threadIdx.x;
  const float* sp = src + ((size_t)p * DIM_ + c0) * HW_;
#pragma unroll
  for (int i = 0; i < 4; ++i) {
    int g = i * 256 + t;
    int ci = g >> 5, s4 = g & 31;
    float4 v = *(const float4*)(sp + (size_t)ci * HW_ + s4 * 4);
    int sb = s4 * 4;
    tile[ci][sb] = v.x; tile[ci][sb + 1] = v.y; tile[ci][sb + 2] = v.z; tile[ci][sb + 3] = v.w;
  }
  __syncthreads();
  // 4 kq-groups x 128 s = 512 cells of 16B; 2 cells per thread.
  unsigned short* dp = dst + (size_t)p * HW_ * DIM_ + (size_t)(c0 >> 3) * 1024;
#pragma unroll
  for (int i = 0; i < 2; ++i) {
    int cidx = i * 256 + t;
    int kg = cidx >> 7, s = cidx & 127;
    u16x8 pk;
#pragma unroll
    for (int u = 0; u < 8; ++u) pk[u] = f2bf(tile[kg * 8 + u][s]);
    *(u16x8*)(dp + (size_t)kg * 1024 + (size_t)s * 8) = pk;
  }
}

// ---------------------------------------------------------------------------
// dist partials: 512 blocks; atomicAdd -2*x.p into dsum[n*64+p], ||p||^2 into
// dsum[1024+p] (zeroed by cvt_all).
// ---------------------------------------------------------------------------
__global__ __launch_bounds__(256)
void dist_partial_kernel(const float* __restrict__ x, const float* __restrict__ proto,
                         float* __restrict__ dsum) {
  __shared__ alignas(16) float xl[16][132];
  __shared__ alignas(16) float pl[64][132];
  const int t = threadIdx.x, b = blockIdx.x;
  const int n0 = t & 7;
  const int pb = t >> 3;
  float acc[2][2] = {};
  float pn = 0.f;

  for (int sc = 0; sc < 4; ++sc) {
    const int k0 = b * 512 + sc * 128;
#pragma unroll
    for (int it = 0; it < 2; ++it) {
      int f = it * 256 + t;
      int row = f >> 5, s4 = f & 31;
      *(float4*)&xl[row][s4 * 4] = *(const float4*)(x + (size_t)row * KFULL + k0 + s4 * 4);
    }
#pragma unroll
    for (int it = 0; it < 8; ++it) {
      int f = it * 256 + t;
      int row = f >> 5, s4 = f & 31;
      *(float4*)&pl[row][s4 * 4] = *(const float4*)(proto + (size_t)row * KFULL + k0 + s4 * 4);
    }
    __syncthreads();

#pragma unroll 4
    for (int k = 0; k < 128; k += 4) {
      float4 xa = *(float4*)&xl[n0][k];
      float4 xb = *(float4*)&xl[n0 + 8][k];
      float4 p0 = *(float4*)&pl[pb][k];
      float4 p1 = *(float4*)&pl[pb + 32][k];
      acc[0][0] += xa.x*p0.x + xa.y*p0.y + xa.z*p0.z + xa.w*p0.w;
      acc[0][1] += xa.x*p1.x + xa.y*p1.y + xa.z*p1.z + xa.w*p1.w;
      acc[1][0] += xb.x*p0.x + xb.y*p0.y + xb.z*p0.z + xb.w*p0.w;
      acc[1][1] += xb.x*p1.x + xb.y*p1.y + xb.z*p1.z + xb.w*p1.w;
    }
    if (t < 64) {
#pragma unroll 4
      for (int k = 0; k < 128; k += 4) {
        float4 pv = *(float4*)&pl[t][k];
        pn += pv.x*pv.x + pv.y*pv.y + pv.z*pv.z + pv.w*pv.w;
      }
    }
    __syncthreads();
  }

  atomicAdd(&dsum[n0 * 64 + pb],        -2.f * acc[0][0]);
  atomicAdd(&dsum[n0 * 64 + pb + 32],   -2.f * acc[0][1]);
  atomicAdd(&dsum[(n0+8) * 64 + pb],    -2.f * acc[1][0]);
  atomicAdd(&dsum[(n0+8) * 64 + pb+32], -2.f * acc[1][1]);
  if (t < 64) atomicAdd(&dsum[1024 + t], pn);
}

// ---------------------------------------------------------------------------
// select: rank-based, fully parallel. Block n (16 blocks x 64 lanes): lane p
// ranks its dist among all 64 (stable argsort order); rank<10 -> idx[n][rank].
// flags[] pre-zeroed by cvt_all; benign same-value race across blocks.
// ---------------------------------------------------------------------------
__global__ __launch_bounds__(64)
void select_kernel(const float* __restrict__ dsum, int* __restrict__ idx,
                   int* __restrict__ flags) {
  __shared__ float sh[64];
  const int n = blockIdx.x, t = threadIdx.x;
  float dval = dsum[1024 + t] + dsum[n * 64 + t];
  sh[t] = dval;
  __syncthreads();
  int rank = 0;
#pragma unroll
  for (int j = 0; j < 64; ++j) {
    float o = sh[j];
    rank += (o < dval || (o == dval && j < t)) ? 1 : 0;
  }
  if (rank < TOPK_) { idx[n * TOPK_ + rank] = t; flags[t] = 1; }
}

// ---------------------------------------------------------------------------
// bf16 MFMA GEMM, tile 64Mx128Nx64K, 128 threads = 2 waves, wave-tile 64x64
// = 4x4 of 16x16x32. Triple-buffered LDS, 2-deep prefetch, counted vmcnt
// (stage-(it+1) loads stay in flight across the raw s_barrier) — round-2
// structure kept.
//
// Round-3 change: ALL global tensors this kernel stages are now k-quad-major
// (W'[kq][O][8], X'[batch][kq][s][8]) so every global_load_lds reads ONE
// contiguous 1KB run (8 cache lines) instead of a 64-line gather at 4KB lane
// stride. Epilogue stores likewise write 2x256B contiguous chunks instead of
// 64 lines. This attacks the measured ~5000-cyc/iter floor (TA line
// throughput), which occupancy (r1) and latency-hiding (r2) did not.
//
// LDS unchanged: A cell(qk,m)=16B @ qk*1024B + m*16B; B cell(qk,n) =
// qk*2048B + n*16B. 3 x (8KB A + 16KB B) = 72 KB -> 2 blocks/CU.
// ---------------------------------------------------------------------------
#define BM 64
#define BKK 64

template <int MODE>
__global__ __launch_bounds__(128, 2)
void mfma_gemm_kernel(const unsigned short* __restrict__ Wb,
                      const unsigned short* __restrict__ Xb,
                      void* __restrict__ OutP,
                      const float* __restrict__ inputs,
                      const int* __restrict__ idxp,
                      const int* __restrict__ flags,
                      int K, int O, int Ldim) {
  __shared__ alignas(16) unsigned short Al[3][8 * BM * 8];    // 3 x 8 KB
  __shared__ alignas(16) unsigned short Bl[3][8 * 128 * 8];   // 3 x 16 KB

  const int t = threadIdx.x;
  const int w = t >> 6;          // wave 0/1 -> n-half
  const int lane = t & 63;
  const int q = lane >> 4;
  const int l15 = lane & 15;
  const int batch = blockIdx.y;
  const int o0 = blockIdx.x * BM;

  if (MODE == 0 && flags && !flags[batch]) return;

  int idreg = 0;
  if (MODE == 1 && lane < TOPK_) idreg = idxp[batch * TOPK_ + lane];

  f32x4 acc[4][4] = {};

  auto issue = [&](int k0, int buf) {
    // A: wave w stages k-quads 4w..4w+3; each load = contiguous 1KB of
    // W'[kq][O][8] starting at output-row o0 (lane*16B appended by HW).
#pragma unroll
    for (int i = 0; i < 4; ++i) {
      int qk = w * 4 + i;
      const unsigned short* ga =
          Wb + (size_t)((k0 >> 3) + qk) * (O * 8) + (size_t)(o0 + lane) * 8;
      __builtin_amdgcn_global_load_lds((const AS1 void*)ga,
                                       (AS3 void*)(&Al[buf][qk * 512]), 16, 0, 0);
    }
    const unsigned short* base;
    if (MODE == 1) {
      int id = __shfl(idreg, k0 >> 8, 64);
      base = Xb + (size_t)id * (HW_ * RF_) + (size_t)((k0 & 255) >> 3) * 1024;
    } else {
      base = Xb + (size_t)batch * HW_ * K + (size_t)(k0 >> 3) * 1024;
    }
    // B: wave w stages 8 of 16 (qk, half) 1KB regions of X'[kq][s][8].
#pragma unroll
    for (int i = 0; i < 8; ++i) {
      int v = w * 8 + i;
      int qk = v >> 1, h = v & 1;
      const unsigned short* gb = base + (size_t)qk * 1024 + (size_t)(h * 64 + lane) * 8;
      __builtin_amdgcn_global_load_lds((const AS1 void*)gb,
                                       (AS3 void*)(&Bl[buf][qk * 1024 + h * 512]), 16, 0, 0);
    }
  };

  const int nIter = K / BKK;   // 32 (MODE 0/2/3) or 40 (MODE 1)

  issue(0, 0);
  issue(BKK, 1);               // 24 loads/wave outstanding

  for (int it = 0; it < nIter; ++it) {
    const int buf = it % 3;
    // Counted wait: stage-it loads (oldest 12) landed; stage-(it+1) loads
    // stay in flight across the barrier. Full drain only on the last iter.
    if (it + 1 < nIter) {
      asm volatile("s_waitcnt vmcnt(12)" ::: "memory");
    } else {
      asm volatile("s_waitcnt vmcnt(0)" ::: "memory");
    }
    __builtin_amdgcn_s_barrier();
#pragma unroll
    for (int s = 0; s < 2; ++s) {
      bf16x8 af[4], bfr[4];
#pragma unroll
      for (int mt = 0; mt < 4; ++mt)
        af[mt] = *(const bf16x8*)(&Al[buf][(s * 4 + q) * 512 + (mt * 16 + l15) * 8]);
#pragma unroll
      for (int nt = 0; nt < 4; ++nt)
        bfr[nt] = *(const bf16x8*)(&Bl[buf][(s * 4 + q) * 1024 + (w * 64 + nt * 16 + l15) * 8]);
#pragma unroll
      for (int mt = 0; mt < 4; ++mt)
#pragma unroll
        for (int nt = 0; nt < 4; ++nt)
          acc[mt][nt] = __builtin_amdgcn_mfma_f32_16x16x32_bf16(af[mt], bfr[nt], acc[mt][nt], 0, 0, 0);
    }
    if (it + 2 < nIter) issue((it + 2) * BKK, (it + 2) % 3);
  }

  // ---------------- epilogue ----------------
  const float CAL = 1.0f - 1.0f / 262144.0f;

  // MODE2 scratch aliases Al buffer 0 (safe: last K-stage uses buffer 1).
  float* nsumS = (float*)&Al[0][0];         // [2][64]
  float* nsqS  = (float*)&Al[0][0] + 128;   // [2][64]

  if (MODE == 2) {
#pragma unroll
    for (int mt = 0; mt < 4; ++mt)
#pragma unroll
      for (int reg = 0; reg < 4; ++reg) {
        float s_ = 0.f, q_ = 0.f;
#pragma unroll
        for (int nt = 0; nt < 4; ++nt) {
          float v = acc[mt][nt][reg];
          s_ += v; q_ += v * v;
        }
#pragma unroll
        for (int m = 1; m < 16; m <<= 1) {
          s_ += __shfl_xor(s_, m, 64);
          q_ += __shfl_xor(q_, m, 64);
        }
        if (l15 == 0) {
          int ol = mt * 16 + q * 4 + reg;
          nsumS[w * 64 + ol] = s_; nsqS[w * 64 + ol] = q_;
        }
      }
    __syncthreads();
  }

  if (MODE == 3) {
    float* ofb = (float*)OutP + (size_t)batch * DIM_ * HW_;
    const float* inb = inputs + (size_t)batch * DIM_ * HW_;
#pragma unroll
    for (int mt = 0; mt < 4; ++mt)
#pragma unroll
      for (int nt = 0; nt < 4; ++nt) {
        int o = o0 + mt * 16 + q * 4;
        int s = w * 64 + nt * 16 + l15;
        f32x4 v = acc[mt][nt];
#pragma unroll
        for (int g = 0; g < 4; ++g) {
          float in = inb[(size_t)(o + g) * HW_ + s];
          float sg = 1.f / (1.f + expf(-v[g]));
          ofb[(size_t)(o + g) * HW_ + s] = in * (1.f + sg);
        }
      }
  } else {
    // Store to X'[batch][o/8][s][8] (k-quad-major): ushort4 at
    // (o>>3)*1024 + s*8 + (o&7); (o&7) in {0,4}. Contiguous 256B per
    // 16-lane group instead of a 64-line scatter.
    unsigned short* ob = (unsigned short*)OutP + (size_t)batch * HW_ * Ldim;
    const float* inb = (MODE == 1) ? inputs + (size_t)batch * DIM_ * HW_ : nullptr;
#pragma unroll
    for (int mt = 0; mt < 4; ++mt) {
      float mean[4], rs[4];
      if (MODE == 2) {
#pragma unroll
        for (int reg = 0; reg < 4; ++reg) {
          int ol = mt * 16 + q * 4 + reg;
          float ts = nsumS[ol] + nsumS[64 + ol];
          float tq = nsqS[ol] + nsqS[64 + ol];
          float mn = ts * (1.f / 128.f);
          float vr = tq * (1.f / 128.f) - mn * mn;
          mean[reg] = mn; rs[reg] = rsqrtf(vr + 1e-5f);
        }
      }
#pragma unroll
      for (int nt = 0; nt < 4; ++nt) {
        int o = o0 + mt * 16 + q * 4;
        int s = w * 64 + nt * 16 + l15;
        f32x4 v = acc[mt][nt];
        float r[4];
        if (MODE == 0) {
#pragma unroll
          for (int g = 0; g < 4; ++g) r[g] = v[g];
        } else if (MODE == 1) {
          const float* ip = inb + (size_t)o * HW_ + s;
#pragma unroll
          for (int g = 0; g < 4; ++g)
            r[g] = fmaxf(0.f, 0.5f * ip[(size_t)g * HW_] + CAL * v[g]);
        } else {
#pragma unroll
          for (int g = 0; g < 4; ++g) r[g] = (v[g] - mean[g]) * rs[g];
        }
        ushort4 pk;
        pk.x = f2bf(r[0]); pk.y = f2bf(r[1]); pk.z = f2bf(r[2]); pk.w = f2bf(r[3]);
        *(ushort4*)(ob + (size_t)(o >> 3) * 1024 + (size_t)s * 8 + (o & 7)) = pk;
      }
    }
  }
}

// ---------------------------------------------------------------------------
extern "C" void kernel_launch(void* const* d_in, const int* in_sizes, int n_in,
                              void* d_out, int out_size, void* d_ws, size_t ws_size,
                              hipStream_t stream) {
  const float* inputs = (const float*)d_in[0];
  const float* proto  = (const float*)d_in[1];
  const float* w_rf   = (const float*)d_in[2];
  const float* w_rfmv = (const float*)d_in[3];
  const float* w_rms  = (const float*)d_in[4];
  const float* w_fuse = (const float*)d_in[5];
  float* out = (float*)d_out;

  uint8_t* ws = (uint8_t*)d_ws;
  size_t off = 0;
  auto alloc = [&](size_t bytes) { uint8_t* p = ws + off; off += (bytes + 255) & ~(size_t)255; return p; };

  float* dsum  = (float*)alloc(1088 * 4);       // 4352 B (256-aligned size)
  int*   flags = (int*)alloc(PN_ * 4);          // contiguous after dsum -> zeroed together
  int*   idx   = (int*)alloc(N_ * TOPK_ * 4);
  unsigned short* wrf_b   = (unsigned short*)alloc((size_t)RF_ * DIM_ * 2);
  unsigned short* wrfmv_b = (unsigned short*)alloc((size_t)DIM_ * KMV * 2);
  unsigned short* wrms_b  = (unsigned short*)alloc((size_t)DIM_ * DIM_ * 2);
  unsigned short* wfuse_b = (unsigned short*)alloc((size_t)DIM_ * DIM_ * 2);
  unsigned short* xpT     = (unsigned short*)alloc((size_t)PN_ * HW_ * RF_ * 2);
  unsigned short* protoT  = (unsigned short*)alloc((size_t)PN_ * HW_ * DIM_ * 2);
  unsigned short* mvlT = protoT;                 // aliases (protoT dead after G1)
  unsigned short* mvaT = protoT + (size_t)N_ * HW_ * DIM_;

  cvt_all_kernel<<<1024, 256, 0, stream>>>(w_rf, w_rfmv, w_rms, w_fuse,
                                           wrf_b, wrfmv_b, wrms_b, wfuse_b, dsum);
  transpose_proto_kernel<<<dim3(PN_, DIM_ / 32), 256, 0, stream>>>(proto, protoT);
  dist_partial_kernel<<<512, 256, 0, stream>>>(inputs, proto, dsum);
  select_kernel<<<N_, 64, 0, stream>>>(dsum, idx, flags);

  mfma_gemm_kernel<0><<<dim3(RF_ / BM, PN_), 128, 0, stream>>>(
      wrf_b, protoT, xpT, nullptr, nullptr, flags, DIM_, RF_, RF_);
  mfma_gemm_kernel<1><<<dim3(DIM_ / BM, N_), 128, 0, stream>>>(
      wrfmv_b, xpT, mvlT, inputs, idx, nullptr, KMV, DIM_, DIM_);
  mfma_gemm_kernel<2><<<dim3(DIM_ / BM, N_), 128, 0, stream>>>(
      wrms_b, mvlT, mvaT, nullptr, nullptr, nullptr, DIM_, DIM_, DIM_);
  mfma_gemm_kernel<3><<<dim3(DIM_ / BM, N_), 128, 0, stream>>>(
      wfuse_b, mvaT, out, inputs, nullptr, nullptr, DIM_, DIM_, DIM_);
}